// Round 17
// baseline (314.126 us; speedup 1.0000x reference)
//
#include <hip/hip_runtime.h>
#include <hip/hip_fp16.h>
#include <stdint.h>

typedef _Float16 half8 __attribute__((ext_vector_type(8)));
typedef _Float16 half4v __attribute__((ext_vector_type(4)));
typedef float floatx4 __attribute__((ext_vector_type(4)));
typedef float floatx16 __attribute__((ext_vector_type(16)));

// ---------------------------------------------------------------------------
// async global->LDS copy, 16B per lane. LDS dest = wave-uniform base + lane*16.
__device__ inline void gload_lds16(const void* g, void* l) {
    __builtin_amdgcn_global_load_lds(
        (const __attribute__((address_space(1))) uint32_t*)g,
        (__attribute__((address_space(3))) uint32_t*)l, 16, 0, 0);
}

// ---------------------------------------------------------------------------
// XCD-aware chunked block swizzle (T1): XCD k owns a contiguous chunk of
// tile-space -> same-row tiles share one L2.  Requires nwg % 8 == 0.
__device__ inline void xcd_swizzle(int nx, int& bx, int& by) {
    const int nwg  = nx * gridDim.y;
    const int orig = by * nx + bx;
    const int cpx  = nwg >> 3;
    const int t    = (orig & 7) * cpx + (orig >> 3);
    bx = t % nx;
    by = t / nx;
}

// ---------------------------------------------------------------------------
// Fused split-cast for all four flat inputs (A-style [hi|lo|hi] / B-style
// [hi|hi|lo] Markidis-3 layouts, row width nc, out stride 3*nc).
__global__ __launch_bounds__(256) void split_cast_all(
    const float* __restrict__ x1, _Float16* __restrict__ x1cat,
    const float* __restrict__ x2, _Float16* __restrict__ x2cat,
    const float* __restrict__ Wk, _Float16* __restrict__ Wkcat,
    const float* __restrict__ Wq, _Float16* __restrict__ Wqcat,
    int nc, int n1, int n2) {
    int i = (blockIdx.x * 256 + threadIdx.x) * 4;
    const float* src;
    _Float16* out;
    bool astyle;
    if (i < 2 * n1) {
        astyle = (i < n1);
        const int ii = astyle ? i : i - n1;
        src = (astyle ? x1 : x2) + ii;
        out = astyle ? x1cat : x2cat;
        i = ii;
    } else {
        int j = i - 2 * n1;
        if (j >= 2 * n2) return;
        astyle = (j < n2);
        const int ii = astyle ? j : j - n2;
        src = (astyle ? Wk : Wq) + ii;
        out = astyle ? Wkcat : Wqcat;
        i = ii;
    }
    float4 v = *(const float4*)src;
    int r = i / nc, c = i % nc;
    half4v hi, lo;
    hi[0] = (_Float16)v.x; lo[0] = (_Float16)(v.x - (float)hi[0]);
    hi[1] = (_Float16)v.y; lo[1] = (_Float16)(v.y - (float)hi[1]);
    hi[2] = (_Float16)v.z; lo[2] = (_Float16)(v.z - (float)hi[2]);
    hi[3] = (_Float16)v.w; lo[3] = (_Float16)(v.w - (float)hi[3]);
    size_t base = (size_t)r * 3 * nc;
    if (astyle) {
        *(half4v*)(out + base + c) = hi;
        *(half4v*)(out + base + nc + c) = lo;
        *(half4v*)(out + base + 2 * nc + c) = hi;
    } else {
        *(half4v*)(out + base + c) = hi;
        *(half4v*)(out + base + nc + c) = hi;
        *(half4v*)(out + base + 2 * nc + c) = lo;
    }
}

// ---------------------------------------------------------------------------
// transpose + B-style split cat [hi | hi | lo]: out[n][...]=f(in[k][n]).
__global__ __launch_bounds__(256) void transpose_split_b(
    const float* __restrict__ in, _Float16* __restrict__ out, int dim) {
    __shared__ float tile[32][33];
    const int tx = threadIdx.x, ty = threadIdx.y;
    const int bx = blockIdx.x * 32, by = blockIdx.y * 32;
#pragma unroll
    for (int i = 0; i < 32; i += 8)
        tile[ty + i][tx] = in[(size_t)(by + ty + i) * dim + bx + tx];
    __syncthreads();
#pragma unroll
    for (int i = 0; i < 32; i += 8) {
        float v = tile[tx][ty + i];
        _Float16 hi = (_Float16)v;
        _Float16 lo = (_Float16)(v - (float)hi);
        size_t o = (size_t)(bx + ty + i) * 3 * dim + by + tx;
        out[o] = hi;
        out[o + dim] = hi;
        out[o + 2 * dim] = lo;
    }
}

// ---------------------------------------------------------------------------
// 128x128-tile, 512-thread / 8-wave (4M x 2N) GEMM: C = A @ B^T.
template <int OMODE>
__global__ __launch_bounds__(512) void gemm_bt8(
    const _Float16* __restrict__ A, const _Float16* __restrict__ B,
    void* __restrict__ Cout, int M, int N, int K, int lda, int ldb,
    float cscale) {
    __shared__ _Float16 As[128 * 64];
    __shared__ _Float16 Bs[128 * 64];

    const int tid  = threadIdx.x;
    const int lane = tid & 63;
    const int wid  = tid >> 6;
    const int wr   = wid >> 1;
    const int wc   = wid & 1;
    int bx = blockIdx.x, by = blockIdx.y;
    xcd_swizzle(gridDim.x, bx, by);
    const int row0 = by * 128;
    const int col0 = bx * 128;

    floatx4 acc[2][4] = {};

    const int srow   = lane >> 3;
    const int schunk = (lane & 7) ^ srow;
    const char* gA = (const char*)(A + (size_t)(row0 + wid * 8 + srow) * lda) + schunk * 16;
    const char* gB = (const char*)(B + (size_t)(col0 + wid * 8 + srow) * ldb) + schunk * 16;
    char* lA = (char*)As + (wid * 8) * 128;
    char* lB = (char*)Bs + (wid * 8) * 128;

    const int frow   = lane & 15;
    const int rxor   = frow & 7;
    const int kchunk = lane >> 4;

    const int kTiles = K >> 6;
    for (int kt = 0; kt < kTiles; ++kt) {
        const size_t kb = (size_t)(kt << 6) * 2;
#pragma unroll
        for (int r = 0; r < 2; ++r) {
            gload_lds16(gA + (size_t)(r * 64) * lda * 2 + kb, lA + r * 64 * 128);
            gload_lds16(gB + (size_t)(r * 64) * ldb * 2 + kb, lB + r * 64 * 128);
        }
        __syncthreads();
#pragma unroll
        for (int kk = 0; kk < 2; ++kk) {
            half8 af[2], bf[4];
            const int pc = ((kk * 4 + kchunk) ^ rxor) * 16;
#pragma unroll
            for (int mi = 0; mi < 2; ++mi)
                af[mi] = *(const half8*)((const char*)As + (wr * 32 + mi * 16 + frow) * 128 + pc);
#pragma unroll
            for (int ni = 0; ni < 4; ++ni)
                bf[ni] = *(const half8*)((const char*)Bs + (wc * 64 + ni * 16 + frow) * 128 + pc);
#pragma unroll
            for (int mi = 0; mi < 2; ++mi)
#pragma unroll
                for (int ni = 0; ni < 4; ++ni)
                    acc[mi][ni] = __builtin_amdgcn_mfma_f32_16x16x32_f16(
                        af[mi], bf[ni], acc[mi][ni], 0, 0, 0);
        }
        __syncthreads();
    }

    const int orow0 = row0 + wr * 32 + ((lane >> 4) << 2);
    const int ocol0 = col0 + wc * 64 + (lane & 15);
#pragma unroll
    for (int mi = 0; mi < 2; ++mi) {
#pragma unroll
        for (int ni = 0; ni < 4; ++ni) {
#pragma unroll
            for (int j = 0; j < 4; ++j) {
                const int rr = orow0 + mi * 16 + j;
                const int cc = ocol0 + ni * 16;
                const float v = acc[mi][ni][j] * cscale;
                if (OMODE == 1) {
                    ((_Float16*)Cout)[(size_t)cc * M + rr] = (_Float16)v;
                } else if (OMODE == 3) {
                    ((float*)Cout)[(size_t)rr * N + cc] = v;
                } else {
                    _Float16 hi = (_Float16)v;
                    _Float16 lo = (_Float16)(v - (float)hi);
                    _Float16* o = (_Float16*)Cout + (size_t)rr * 3 * N + cc;
                    if (OMODE == 4) { o[0] = hi; o[N] = lo; o[2 * N] = hi; }
                    else            { o[0] = hi; o[N] = hi; o[2 * N] = lo; }
                }
            }
        }
    }
}

// ---------------------------------------------------------------------------
// 256x256-tile, BK=64, 8-wave (2Mx4N), 4 phases/K-tile, R12 spread staging +
// counted vmcnt(6) -- NOW with 32x32x16 MFMA (2x FLOP per operand register,
// ceiling 2382 vs 2075 TF).  Per wave: 128x64 = 4x2 tiles of 32x32,
// acc[4][2] f32x16 (128 AGPR, same as before).  Phases keep (kk, M-half)
// semantics so the dead-region staging and vmcnt ledger are unchanged.
// Frag layouts: A/B row = lane&31, k = 8*(lane>>5)+j (same K-major family as
// the verified 16x16 map); C/D col = lane&31, row = (reg&3)+8*(reg>>2)+
// 4*(lane>>5)  [guide m74/m101-verified].
#define SB0() __builtin_amdgcn_sched_barrier(0)
#define BAR() __builtin_amdgcn_s_barrier()

// A frags for (KK, MH): af[mtl][ks], rows wr*128 + MH*64 + mtl*32 + lane31
#define RD_A32(KK, MH)                                                        \
    _Pragma("unroll")                                                         \
    for (int mtl = 0; mtl < 2; ++mtl)                                         \
        _Pragma("unroll")                                                     \
        for (int ks = 0; ks < 2; ++ks)                                        \
            af[mtl][ks] = *(const half8*)(bsA +                               \
                (wr * 128 + (MH) * 64 + mtl * 32 + lane31) * 128 +            \
                ((((KK) * 4 + ks * 2 + lhalf) ^ rx) * 16));

// B frags for (KK): bf[nt][ks], rows wc*64 + nt*32 + lane31
#define RD_B32(KK)                                                            \
    _Pragma("unroll")                                                         \
    for (int nt = 0; nt < 2; ++nt)                                            \
        _Pragma("unroll")                                                     \
        for (int ks = 0; ks < 2; ++ks)                                        \
            bf[nt][ks] = *(const half8*)(bsB +                                \
                (wc * 64 + nt * 32 + lane31) * 128 +                          \
                ((((KK) * 4 + ks * 2 + lhalf) ^ rx) * 16));

#define PH_MFMA32(MH)                                                         \
    __builtin_amdgcn_s_setprio(1);                                            \
    _Pragma("unroll")                                                         \
    for (int ks = 0; ks < 2; ++ks)                                            \
        _Pragma("unroll")                                                     \
        for (int mtl = 0; mtl < 2; ++mtl)                                     \
            _Pragma("unroll")                                                 \
            for (int nt = 0; nt < 2; ++nt)                                    \
                acc[(MH) * 2 + mtl][nt] =                                     \
                    __builtin_amdgcn_mfma_f32_32x32x16_f16(                   \
                        af[mtl][ks], bf[nt][ks], acc[(MH) * 2 + mtl][nt],     \
                        0, 0, 0);                                             \
    __builtin_amdgcn_s_setprio(0);

#define STG_A(DST, tt, i)                                                     \
    gload_lds16(gA + (size_t)((i) * 64) * lda + (size_t)(tt) * 64,            \
                (char*)(DST) + (wid * 8 + (i) * 64) * 128);
#define STG_B(DST, tt, i)                                                     \
    gload_lds16(gB + (size_t)((i) * 64) * ldb + (size_t)(tt) * 64,            \
                (char*)(DST) + (wid * 8 + (i) * 64) * 128);

__global__ __launch_bounds__(512, 2) void gemm256_bt_f32(
    const _Float16* __restrict__ A, const _Float16* __restrict__ B,
    float* __restrict__ C, int M, int N, int K, int lda, int ldb,
    float cscale) {
    __shared__ _Float16 As[2][256 * 64];   // 2 x 32 KiB
    __shared__ _Float16 Bs[2][256 * 64];   // 2 x 32 KiB  (total 128 KiB)

    const int tid  = threadIdx.x;
    const int lane = tid & 63;
    const int wid  = tid >> 6;     // 0..7
    const int wr   = wid >> 2;     // 0..1  M-half of block tile (128 rows)
    const int wc   = wid & 3;      // 0..3  N-quarter (64 cols)
    int bx = blockIdx.x, by = blockIdx.y;
    xcd_swizzle(gridDim.x, bx, by);
    const int row0 = by * 256;
    const int col0 = bx * 256;

    floatx16 acc[4][2] = {};       // [Mtile 32-rows][Ntile 32-cols]

    const int srow   = lane >> 3;
    const int schunk = (lane & 7) ^ srow;    // pre-swizzled global source
    const _Float16* gA = A + (size_t)(row0 + wid * 8 + srow) * lda + schunk * 8;
    const _Float16* gB = B + (size_t)(col0 + wid * 8 + srow) * ldb + schunk * 8;

    const int lane31 = lane & 31;
    const int lhalf  = lane >> 5;
    const int rx     = lane & 7;   // (row & 7) since row = lane31

    const int NT = K >> 6;

    // prologue: stage tiles 0 and 1 fully; wait tile 0 (tile 1's 8 in flight)
#pragma unroll
    for (int i = 0; i < 4; ++i) { STG_A((char*)As[0], 0, i) STG_B((char*)Bs[0], 0, i) }
#pragma unroll
    for (int i = 0; i < 4; ++i) { STG_A((char*)As[1], 1, i) STG_B((char*)Bs[1], 1, i) }
    asm volatile("s_waitcnt vmcnt(8)" ::: "memory");
    SB0();
    BAR();

    half8 af[2][2], bf[2][2];
    for (int t = 0; t < NT; ++t) {
        const int d = t & 1;
        char* curA = (char*)As[0] + d * 32768;
        char* curB = (char*)Bs[0] + d * 32768;
        char* nxtA = (char*)As[0] + (d ^ 1) * 32768;
        const char* bsA = curA;
        const char* bsB = curB;

        // ---- P0: kk0, MH0 (+B kk0); finish staging tile t+1's A-MH1 into nxt
        RD_A32(0, 0)
        RD_B32(0)
        if (t >= 1 && t + 1 < NT) { STG_A(nxtA, t + 1, 1) STG_A(nxtA, t + 1, 3) }
        SB0();
        BAR();
        asm volatile("s_waitcnt lgkmcnt(0)" ::: "memory");
        SB0();
        PH_MFMA32(0)
        BAR();

        // ---- P1: kk0, MH1 (B kk0 frags reused)
        RD_A32(0, 1)
        SB0();
        BAR();
        asm volatile("s_waitcnt lgkmcnt(0)" ::: "memory");
        SB0();
        PH_MFMA32(1)
        BAR();

        // ---- P2: kk1, MH0 (+B kk1)
        RD_A32(1, 0)
        RD_B32(1)
        SB0();
        BAR();
        asm volatile("s_waitcnt lgkmcnt(0)" ::: "memory");
        SB0();
        PH_MFMA32(0)
        BAR();

        // ---- P3: kk1, MH1; stage 6 of tile t+2 into dead regions of cur
        RD_A32(1, 1)
        const bool pf = (t + 2 < NT);
        if (pf) {
            STG_B(curB, t + 2, 0) STG_B(curB, t + 2, 1)
            STG_B(curB, t + 2, 2) STG_B(curB, t + 2, 3)
            STG_A(curA, t + 2, 0) STG_A(curA, t + 2, 2)
        }
        SB0();
        BAR();
        asm volatile("s_waitcnt lgkmcnt(0)" ::: "memory");
        SB0();
        if (pf) { asm volatile("s_waitcnt vmcnt(6)" ::: "memory"); }
        else    { asm volatile("s_waitcnt vmcnt(0)" ::: "memory"); }
        SB0();
        PH_MFMA32(1)
        BAR();   // tile t+1 resident; its A-MH1 region (cur) now dead
    }

    // epilogue: 32x32 C/D map: col = lane31, row = (reg&3)+8*(reg>>2)+4*lhalf
    const int orow0 = row0 + wr * 128 + 4 * lhalf;
    const int ocol0 = col0 + wc * 64 + lane31;
#pragma unroll
    for (int mt = 0; mt < 4; ++mt) {
#pragma unroll
        for (int nt = 0; nt < 2; ++nt) {
#pragma unroll
            for (int reg = 0; reg < 16; ++reg) {
                const int rr = orow0 + mt * 32 + (reg & 3) + 8 * (reg >> 2);
                const int cc = ocol0 + nt * 32;
                C[(size_t)rr * N + cc] = acc[mt][nt][reg] * cscale;
            }
        }
    }
}

// ---------------------------------------------------------------------------
// row softmax over f32 S (already scaled /32), in place: writes normalized
// P = exp(s-m)/sum as f16 at the same row base (row stride ncols f32 slots).
__global__ __launch_bounds__(256) void softmax_inplace(
    float* __restrict__ S, int ncols) {
    const int row = blockIdx.x;
    float* srow = S + (size_t)row * ncols;
    const int t = threadIdx.x;

    float x[16];
#pragma unroll
    for (int q = 0; q < 4; ++q) {
        float4 v = *(float4*)(srow + t * 16 + q * 4);
        x[q * 4 + 0] = v.x; x[q * 4 + 1] = v.y;
        x[q * 4 + 2] = v.z; x[q * 4 + 3] = v.w;
    }
    float m = x[0];
#pragma unroll
    for (int j = 1; j < 16; ++j) m = fmaxf(m, x[j]);
#pragma unroll
    for (int off = 32; off; off >>= 1) m = fmaxf(m, __shfl_xor(m, off));
    __shared__ float redm[4];
    if ((t & 63) == 0) redm[t >> 6] = m;
    __syncthreads();
    m = fmaxf(fmaxf(redm[0], redm[1]), fmaxf(redm[2], redm[3]));

    float s = 0.0f;
#pragma unroll
    for (int j = 0; j < 16; ++j) {
        x[j] = __expf(x[j] - m);
        s += x[j];
    }
#pragma unroll
    for (int off = 32; off; off >>= 1) s += __shfl_xor(s, off);
    __shared__ float reds[4];
    if ((t & 63) == 0) reds[t >> 6] = s;
    __syncthreads();
    s = reds[0] + reds[1] + reds[2] + reds[3];
    const float inv = 1.0f / s;

    _Float16* prow = (_Float16*)srow;
    half8 o0, o1;
#pragma unroll
    for (int j = 0; j < 8; ++j) {
        o0[j] = (_Float16)(x[j] * inv);
        o1[j] = (_Float16)(x[8 + j] * inv);
    }
    __syncthreads();
    *(half8*)(prow + t * 16)     = o0;
    *(half8*)(prow + t * 16 + 8) = o1;
}

// ---------------------------------------------------------------------------
extern "C" void kernel_launch(void* const* d_in, const int* in_sizes, int n_in,
                              void* d_out, int out_size, void* d_ws, size_t ws_size,
                              hipStream_t stream) {
    const float* x1 = (const float*)d_in[0];
    const float* x2 = (const float*)d_in[1];
    const float* Wq = (const float*)d_in[2];
    const float* Wk = (const float*)d_in[3];
    const float* Wv = (const float*)d_in[4];
    float* out = (float*)d_out;

    const int NQ = 4096, NKV = 4096, D = 1024;

    // workspace (MB).  S (0..64) overlays buffers dead before the S GEMM.
    char* ws = (char*)d_ws;
    float*    S      = (float*)ws;                       //   0..64
    _Float16* x1cat  = (_Float16*)(ws);                  //   0..24  A-style (dead after T)
    _Float16* Wqcat  = (_Float16*)(ws + (24u  << 20));   //  24..30  B-style (dead after Mt)
    _Float16* Wkcat  = (_Float16*)(ws + (30u  << 20));   //  30..36  A-style (dead after Mt)
    _Float16* Mtcat  = (_Float16*)(ws + (36u  << 20));   //  36..42  B-style (dead after T)
    _Float16* Wvct   = (_Float16*)(ws + (42u  << 20));   //  42..48  B-style (dead after V)
    _Float16* x2cat  = (_Float16*)(ws + (64u  << 20));   //  64..88  B-style (live thru S)
    _Float16* Tcat   = (_Float16*)(ws + (88u  << 20));   //  88..112 A-style (live thru S)
    _Float16* Vt     = (_Float16*)(ws + (112u << 20));   // 112..120 f16 (live thru PV)

    // 1) fused casts: x1->A, x2->B, Wk->A, Wq->B; Wv -> transposed B-style
    const int n1 = NQ * D, n2 = D * D;
    split_cast_all<<<(2 * (n1 + n2) + 1023) / 1024, 256, 0, stream>>>(
        x1, x1cat, x2, x2cat, Wk, Wkcat, Wq, Wqcat, D, n1, n2);
    dim3 tb(32, 8), tg(D / 32, D / 32);
    transpose_split_b<<<tg, tb, 0, stream>>>(Wv, Wvct, D);

    // 2) M^T = Wk @ Wq^T  (split-3 in, B-style split out), 8-wave kernel
    gemm_bt8<5><<<dim3(D / 128, D / 128), 512, 0, stream>>>(
        Wkcat, Wqcat, Mtcat, D, D, 3 * D, 3 * D, 3 * D, 1.0f);

    // 3) T = x1 @ M  (A-style split out) -- replaces BOTH Q and K projections
    gemm_bt8<4><<<dim3(D / 128, NQ / 128), 512, 0, stream>>>(
        x1cat, Mtcat, Tcat, NQ, D, 3 * D, 3 * D, 3 * D, 1.0f);

    // 4) V^T: plain f16, K=1024 (hi segments)
    gemm_bt8<1><<<dim3(D / 128, NKV / 128), 512, 0, stream>>>(
        x2cat, Wvct, Vt, NKV, D, D, 3 * D, 3 * D, 1.0f);

    // 5) scores: S = (T @ x2^T)/32, K=3072, 256^2 kernel with 32x32x16 MFMA
    gemm256_bt_f32<<<dim3(NKV / 256, NQ / 256), 512, 0, stream>>>(
        Tcat, x2cat, S, NQ, NKV, 3 * D, 3 * D, 3 * D, 1.0f / 32.0f);

    // 6) softmax rows in place: f32 scores -> normalized f16 P (stride 8192 f16)
    softmax_inplace<<<NQ, 256, 0, stream>>>(S, NKV);

    // 7) out = P @ V  (A = P f16, lda=8192; B^T = Vt[D][NKV], ldb=4096)
    gemm_bt8<3><<<dim3(D / 128, NQ / 128), 512, 0, stream>>>(
        (const _Float16*)S, Vt, out, NQ, D, NKV, 2 * NKV, NKV, 1.0f);
}

// Round 18
// 308.423 us; speedup vs baseline: 1.0185x; 1.0185x over previous
//
#include <hip/hip_runtime.h>
#include <hip/hip_fp16.h>
#include <stdint.h>

typedef _Float16 half8 __attribute__((ext_vector_type(8)));
typedef _Float16 half4v __attribute__((ext_vector_type(4)));
typedef float floatx4 __attribute__((ext_vector_type(4)));

// ---------------------------------------------------------------------------
// async global->LDS copy, 16B per lane. LDS dest = wave-uniform base + lane*16.
__device__ inline void gload_lds16(const void* g, void* l) {
    __builtin_amdgcn_global_load_lds(
        (const __attribute__((address_space(1))) uint32_t*)g,
        (__attribute__((address_space(3))) uint32_t*)l, 16, 0, 0);
}

// ---------------------------------------------------------------------------
// XCD-aware chunked block swizzle (T1): XCD k owns a contiguous chunk of
// tile-space -> same-row tiles share one L2.  Requires nwg % 8 == 0.
__device__ inline void xcd_swizzle(int nx, int& bx, int& by) {
    const int nwg  = nx * gridDim.y;
    const int orig = by * nx + bx;
    const int cpx  = nwg >> 3;
    const int t    = (orig & 7) * cpx + (orig >> 3);
    bx = t % nx;
    by = t / nx;
}

// ---------------------------------------------------------------------------
// Fused split-cast for all four flat inputs (A-style [hi|lo|hi] / B-style
// [hi|hi|lo] Markidis-3 layouts, row width nc, out stride 3*nc).
__global__ __launch_bounds__(256) void split_cast_all(
    const float* __restrict__ x1, _Float16* __restrict__ x1cat,
    const float* __restrict__ x2, _Float16* __restrict__ x2cat,
    const float* __restrict__ Wk, _Float16* __restrict__ Wkcat,
    const float* __restrict__ Wq, _Float16* __restrict__ Wqcat,
    int nc, int n1, int n2) {
    int i = (blockIdx.x * 256 + threadIdx.x) * 4;
    const float* src;
    _Float16* out;
    bool astyle;
    if (i < 2 * n1) {
        astyle = (i < n1);
        const int ii = astyle ? i : i - n1;
        src = (astyle ? x1 : x2) + ii;
        out = astyle ? x1cat : x2cat;
        i = ii;
    } else {
        int j = i - 2 * n1;
        if (j >= 2 * n2) return;
        astyle = (j < n2);
        const int ii = astyle ? j : j - n2;
        src = (astyle ? Wk : Wq) + ii;
        out = astyle ? Wkcat : Wqcat;
        i = ii;
    }
    float4 v = *(const float4*)src;
    int r = i / nc, c = i % nc;
    half4v hi, lo;
    hi[0] = (_Float16)v.x; lo[0] = (_Float16)(v.x - (float)hi[0]);
    hi[1] = (_Float16)v.y; lo[1] = (_Float16)(v.y - (float)hi[1]);
    hi[2] = (_Float16)v.z; lo[2] = (_Float16)(v.z - (float)hi[2]);
    hi[3] = (_Float16)v.w; lo[3] = (_Float16)(v.w - (float)hi[3]);
    size_t base = (size_t)r * 3 * nc;
    if (astyle) {
        *(half4v*)(out + base + c) = hi;
        *(half4v*)(out + base + nc + c) = lo;
        *(half4v*)(out + base + 2 * nc + c) = hi;
    } else {
        *(half4v*)(out + base + c) = hi;
        *(half4v*)(out + base + nc + c) = hi;
        *(half4v*)(out + base + 2 * nc + c) = lo;
    }
}

// ---------------------------------------------------------------------------
// transpose + B-style split cat [hi | hi | lo]: out[n][...]=f(in[k][n]).
__global__ __launch_bounds__(256) void transpose_split_b(
    const float* __restrict__ in, _Float16* __restrict__ out, int dim) {
    __shared__ float tile[32][33];
    const int tx = threadIdx.x, ty = threadIdx.y;
    const int bx = blockIdx.x * 32, by = blockIdx.y * 32;
#pragma unroll
    for (int i = 0; i < 32; i += 8)
        tile[ty + i][tx] = in[(size_t)(by + ty + i) * dim + bx + tx];
    __syncthreads();
#pragma unroll
    for (int i = 0; i < 32; i += 8) {
        float v = tile[tx][ty + i];
        _Float16 hi = (_Float16)v;
        _Float16 lo = (_Float16)(v - (float)hi);
        size_t o = (size_t)(bx + ty + i) * 3 * dim + by + tx;
        out[o] = hi;
        out[o + dim] = hi;
        out[o + 2 * dim] = lo;
    }
}

// ---------------------------------------------------------------------------
// 128x128-tile, 512-thread / 8-wave (4M x 2N) GEMM: C = A @ B^T.
// Each wave owns a 32x64 sub-tile (acc 2x4) -> 2 waves/SIMD overlap.
template <int OMODE>
__global__ __launch_bounds__(512) void gemm_bt8(
    const _Float16* __restrict__ A, const _Float16* __restrict__ B,
    void* __restrict__ Cout, int M, int N, int K, int lda, int ldb,
    float cscale) {
    __shared__ _Float16 As[128 * 64];
    __shared__ _Float16 Bs[128 * 64];

    const int tid  = threadIdx.x;
    const int lane = tid & 63;
    const int wid  = tid >> 6;
    const int wr   = wid >> 1;
    const int wc   = wid & 1;
    int bx = blockIdx.x, by = blockIdx.y;
    xcd_swizzle(gridDim.x, bx, by);
    const int row0 = by * 128;
    const int col0 = bx * 128;

    floatx4 acc[2][4] = {};

    const int srow   = lane >> 3;
    const int schunk = (lane & 7) ^ srow;
    const char* gA = (const char*)(A + (size_t)(row0 + wid * 8 + srow) * lda) + schunk * 16;
    const char* gB = (const char*)(B + (size_t)(col0 + wid * 8 + srow) * ldb) + schunk * 16;
    char* lA = (char*)As + (wid * 8) * 128;
    char* lB = (char*)Bs + (wid * 8) * 128;

    const int frow   = lane & 15;
    const int rxor   = frow & 7;
    const int kchunk = lane >> 4;

    const int kTiles = K >> 6;
    for (int kt = 0; kt < kTiles; ++kt) {
        const size_t kb = (size_t)(kt << 6) * 2;
#pragma unroll
        for (int r = 0; r < 2; ++r) {
            gload_lds16(gA + (size_t)(r * 64) * lda * 2 + kb, lA + r * 64 * 128);
            gload_lds16(gB + (size_t)(r * 64) * ldb * 2 + kb, lB + r * 64 * 128);
        }
        __syncthreads();
#pragma unroll
        for (int kk = 0; kk < 2; ++kk) {
            half8 af[2], bf[4];
            const int pc = ((kk * 4 + kchunk) ^ rxor) * 16;
#pragma unroll
            for (int mi = 0; mi < 2; ++mi)
                af[mi] = *(const half8*)((const char*)As + (wr * 32 + mi * 16 + frow) * 128 + pc);
#pragma unroll
            for (int ni = 0; ni < 4; ++ni)
                bf[ni] = *(const half8*)((const char*)Bs + (wc * 64 + ni * 16 + frow) * 128 + pc);
#pragma unroll
            for (int mi = 0; mi < 2; ++mi)
#pragma unroll
                for (int ni = 0; ni < 4; ++ni)
                    acc[mi][ni] = __builtin_amdgcn_mfma_f32_16x16x32_f16(
                        af[mi], bf[ni], acc[mi][ni], 0, 0, 0);
        }
        __syncthreads();
    }

    const int orow0 = row0 + wr * 32 + ((lane >> 4) << 2);
    const int ocol0 = col0 + wc * 64 + (lane & 15);
#pragma unroll
    for (int mi = 0; mi < 2; ++mi) {
#pragma unroll
        for (int ni = 0; ni < 4; ++ni) {
#pragma unroll
            for (int j = 0; j < 4; ++j) {
                const int rr = orow0 + mi * 16 + j;
                const int cc = ocol0 + ni * 16;
                const float v = acc[mi][ni][j] * cscale;
                if (OMODE == 1) {
                    ((_Float16*)Cout)[(size_t)cc * M + rr] = (_Float16)v;
                } else if (OMODE == 3) {
                    ((float*)Cout)[(size_t)rr * N + cc] = v;
                } else {
                    _Float16 hi = (_Float16)v;
                    _Float16 lo = (_Float16)(v - (float)hi);
                    _Float16* o = (_Float16*)Cout + (size_t)rr * 3 * N + cc;
                    if (OMODE == 4) { o[0] = hi; o[N] = lo; o[2 * N] = hi; }
                    else            { o[0] = hi; o[N] = hi; o[2 * N] = lo; }
                }
            }
        }
    }
}

// ---------------------------------------------------------------------------
// 256x256-tile, BK=64, 8-wave (2Mx4N), 4 phases/K-tile with PER-PHASE spread
// staging + counted vmcnt(6) + XCD swizzle.  (R16-verified: 109.7 us,
// VGPR 104, MfmaUtil 38-39, 0 bank conflicts.)  16x16x32 MFMA -- the 32x32
// shape was tried (R17) and loses ~10% to inherent 4-way LDS conflicts.
#define SB0() __builtin_amdgcn_sched_barrier(0)
#define BAR() __builtin_amdgcn_s_barrier()

#define PH_READS(KK, MH, DO_B)                                                \
    {                                                                         \
        const int pc_ = (((KK) * 4 + kchunk) ^ rxor) * 16;                    \
        if (DO_B) {                                                           \
            _Pragma("unroll")                                                 \
            for (int ni = 0; ni < 4; ++ni)                                    \
                bf[ni] = *(const half8*)(bsB + (wc * 64 + ni * 16 + frow) * 128 + pc_); \
        }                                                                     \
        _Pragma("unroll")                                                     \
        for (int mi = 0; mi < 4; ++mi)                                        \
            af[mi] = *(const half8*)(bsA + (wr * 128 + ((MH) * 4 + mi) * 16 + frow) * 128 + pc_); \
    }

#define PH_MFMA(MH)                                                           \
    __builtin_amdgcn_s_setprio(1);                                            \
    _Pragma("unroll")                                                         \
    for (int mi = 0; mi < 4; ++mi)                                            \
        _Pragma("unroll")                                                     \
        for (int ni = 0; ni < 4; ++ni)                                        \
            acc[(MH) * 4 + mi][ni] = __builtin_amdgcn_mfma_f32_16x16x32_f16(  \
                af[mi], bf[ni], acc[(MH) * 4 + mi][ni], 0, 0, 0);             \
    __builtin_amdgcn_s_setprio(0);

#define STG_A(DST, tt, i)                                                     \
    gload_lds16(gA + (size_t)((i) * 64) * lda + (size_t)(tt) * 64,            \
                (char*)(DST) + (wid * 8 + (i) * 64) * 128);
#define STG_B(DST, tt, i)                                                     \
    gload_lds16(gB + (size_t)((i) * 64) * ldb + (size_t)(tt) * 64,            \
                (char*)(DST) + (wid * 8 + (i) * 64) * 128);

__global__ __launch_bounds__(512, 2) void gemm256_bt_f32(
    const _Float16* __restrict__ A, const _Float16* __restrict__ B,
    float* __restrict__ C, int M, int N, int K, int lda, int ldb,
    float cscale) {
    __shared__ _Float16 As[2][256 * 64];   // 2 x 32 KiB
    __shared__ _Float16 Bs[2][256 * 64];   // 2 x 32 KiB  (total 128 KiB)

    const int tid  = threadIdx.x;
    const int lane = tid & 63;
    const int wid  = tid >> 6;     // 0..7
    const int wr   = wid >> 2;     // 0..1  M-half
    const int wc   = wid & 3;      // 0..3  N-quarter
    int bx = blockIdx.x, by = blockIdx.y;
    xcd_swizzle(gridDim.x, bx, by);
    const int row0 = by * 256;
    const int col0 = bx * 256;

    floatx4 acc[8][4] = {};

    const int srow   = lane >> 3;
    const int schunk = (lane & 7) ^ srow;    // pre-swizzled global source
    const _Float16* gA = A + (size_t)(row0 + wid * 8 + srow) * lda + schunk * 8;
    const _Float16* gB = B + (size_t)(col0 + wid * 8 + srow) * ldb + schunk * 8;

    const int frow   = lane & 15;
    const int rxor   = frow & 7;
    const int kchunk = lane >> 4;

    const int NT = K >> 6;

    // prologue: stage tiles 0 and 1 fully; wait tile 0 (tile 1's 8 in flight)
#pragma unroll
    for (int i = 0; i < 4; ++i) { STG_A((char*)As[0], 0, i) STG_B((char*)Bs[0], 0, i) }
#pragma unroll
    for (int i = 0; i < 4; ++i) { STG_A((char*)As[1], 1, i) STG_B((char*)Bs[1], 1, i) }
    asm volatile("s_waitcnt vmcnt(8)" ::: "memory");
    SB0();
    BAR();

    half8 af[4], bf[4];
    for (int t = 0; t < NT; ++t) {
        const int d = t & 1;
        char* curA = (char*)As[0] + d * 32768;
        char* curB = (char*)Bs[0] + d * 32768;
        char* nxtA = (char*)As[0] + (d ^ 1) * 32768;
        const char* bsA = curA;
        const char* bsB = curB;

        // ---- P0: kk0, MH0 (+B kk0); then finish staging tile t+1 (A-MH1)
        PH_READS(0, 0, true)
        if (t >= 1 && t + 1 < NT) { STG_A(nxtA, t + 1, 1) STG_A(nxtA, t + 1, 3) }
        SB0();
        BAR();
        asm volatile("s_waitcnt lgkmcnt(0)" ::: "memory");
        SB0();
        PH_MFMA(0)
        BAR();

        // ---- P1: kk0, MH1
        PH_READS(0, 1, false)
        SB0();
        BAR();
        asm volatile("s_waitcnt lgkmcnt(0)" ::: "memory");
        SB0();
        PH_MFMA(1)
        BAR();

        // ---- P2: kk1, MH0 (+B kk1)
        PH_READS(1, 0, true)
        SB0();
        BAR();
        asm volatile("s_waitcnt lgkmcnt(0)" ::: "memory");
        SB0();
        PH_MFMA(0)
        BAR();

        // ---- P3: kk1, MH1; stage 6 of tile t+2 into dead regions of cur
        PH_READS(1, 1, false)
        const bool pf = (t + 2 < NT);
        if (pf) {
            STG_B(curB, t + 2, 0) STG_B(curB, t + 2, 1)
            STG_B(curB, t + 2, 2) STG_B(curB, t + 2, 3)
            STG_A(curA, t + 2, 0) STG_A(curA, t + 2, 2)
        }
        SB0();
        BAR();
        asm volatile("s_waitcnt lgkmcnt(0)" ::: "memory");
        SB0();
        if (pf) { asm volatile("s_waitcnt vmcnt(6)" ::: "memory"); }
        else    { asm volatile("s_waitcnt vmcnt(0)" ::: "memory"); }
        SB0();
        PH_MFMA(1)
        BAR();   // tile t+1 resident; its A-MH1 region (cur) now dead
    }

    // epilogue: D row = 4*(lane>>4)+j, col = lane&15
    const int orow0 = row0 + wr * 128 + ((lane >> 4) << 2);
    const int ocol0 = col0 + wc * 64 + frow;
#pragma unroll
    for (int mi = 0; mi < 8; ++mi) {
#pragma unroll
        for (int ni = 0; ni < 4; ++ni) {
#pragma unroll
            for (int j = 0; j < 4; ++j) {
                const int rr = orow0 + mi * 16 + j;
                const int cc = ocol0 + ni * 16;
                C[(size_t)rr * N + cc] = acc[mi][ni][j] * cscale;
            }
        }
    }
}

// ---------------------------------------------------------------------------
// row softmax over f32 S (already scaled /32), in place: writes normalized
// P = exp(s-m)/sum as f16 at the same row base (row stride ncols f32 slots).
__global__ __launch_bounds__(256) void softmax_inplace(
    float* __restrict__ S, int ncols) {
    const int row = blockIdx.x;
    float* srow = S + (size_t)row * ncols;
    const int t = threadIdx.x;

    float x[16];
#pragma unroll
    for (int q = 0; q < 4; ++q) {
        float4 v = *(float4*)(srow + t * 16 + q * 4);
        x[q * 4 + 0] = v.x; x[q * 4 + 1] = v.y;
        x[q * 4 + 2] = v.z; x[q * 4 + 3] = v.w;
    }
    float m = x[0];
#pragma unroll
    for (int j = 1; j < 16; ++j) m = fmaxf(m, x[j]);
#pragma unroll
    for (int off = 32; off; off >>= 1) m = fmaxf(m, __shfl_xor(m, off));
    __shared__ float redm[4];
    if ((t & 63) == 0) redm[t >> 6] = m;
    __syncthreads();
    m = fmaxf(fmaxf(redm[0], redm[1]), fmaxf(redm[2], redm[3]));

    float s = 0.0f;
#pragma unroll
    for (int j = 0; j < 16; ++j) {
        x[j] = __expf(x[j] - m);
        s += x[j];
    }
#pragma unroll
    for (int off = 32; off; off >>= 1) s += __shfl_xor(s, off);
    __shared__ float reds[4];
    if ((t & 63) == 0) reds[t >> 6] = s;
    __syncthreads();
    s = reds[0] + reds[1] + reds[2] + reds[3];
    const float inv = 1.0f / s;

    _Float16* prow = (_Float16*)srow;
    half8 o0, o1;
#pragma unroll
    for (int j = 0; j < 8; ++j) {
        o0[j] = (_Float16)(x[j] * inv);
        o1[j] = (_Float16)(x[8 + j] * inv);
    }
    __syncthreads();
    *(half8*)(prow + t * 16)     = o0;
    *(half8*)(prow + t * 16 + 8) = o1;
}

// ---------------------------------------------------------------------------
extern "C" void kernel_launch(void* const* d_in, const int* in_sizes, int n_in,
                              void* d_out, int out_size, void* d_ws, size_t ws_size,
                              hipStream_t stream) {
    const float* x1 = (const float*)d_in[0];
    const float* x2 = (const float*)d_in[1];
    const float* Wq = (const float*)d_in[2];
    const float* Wk = (const float*)d_in[3];
    const float* Wv = (const float*)d_in[4];
    float* out = (float*)d_out;

    const int NQ = 4096, NKV = 4096, D = 1024;

    // workspace (MB).  S (0..64) overlays buffers dead before the S GEMM.
    char* ws = (char*)d_ws;
    float*    S      = (float*)ws;                       //   0..64
    _Float16* x1cat  = (_Float16*)(ws);                  //   0..24  A-style (dead after T)
    _Float16* Wqcat  = (_Float16*)(ws + (24u  << 20));   //  24..30  B-style (dead after Mt)
    _Float16* Wkcat  = (_Float16*)(ws + (30u  << 20));   //  30..36  A-style (dead after Mt)
    _Float16* Mtcat  = (_Float16*)(ws + (36u  << 20));   //  36..42  B-style (dead after T)
    _Float16* Wvct   = (_Float16*)(ws + (42u  << 20));   //  42..48  B-style (dead after V)
    _Float16* x2cat  = (_Float16*)(ws + (64u  << 20));   //  64..88  B-style (live thru S)
    _Float16* Tcat   = (_Float16*)(ws + (88u  << 20));   //  88..112 A-style (live thru S)
    _Float16* Vt     = (_Float16*)(ws + (112u << 20));   // 112..120 f16 (live thru PV)

    // 1) fused casts: x1->A, x2->B, Wk->A, Wq->B; Wv -> transposed B-style
    const int n1 = NQ * D, n2 = D * D;
    split_cast_all<<<(2 * (n1 + n2) + 1023) / 1024, 256, 0, stream>>>(
        x1, x1cat, x2, x2cat, Wk, Wkcat, Wq, Wqcat, D, n1, n2);
    dim3 tb(32, 8), tg(D / 32, D / 32);
    transpose_split_b<<<tg, tb, 0, stream>>>(Wv, Wvct, D);

    // 2) M^T = Wk @ Wq^T  (split-3 in, B-style split out), 8-wave kernel
    gemm_bt8<5><<<dim3(D / 128, D / 128), 512, 0, stream>>>(
        Wkcat, Wqcat, Mtcat, D, D, 3 * D, 3 * D, 3 * D, 1.0f);

    // 3) T = x1 @ M  (A-style split out) -- replaces BOTH Q and K projections
    gemm_bt8<4><<<dim3(D / 128, NQ / 128), 512, 0, stream>>>(
        x1cat, Mtcat, Tcat, NQ, D, 3 * D, 3 * D, 3 * D, 1.0f);

    // 4) V^T: plain f16, K=1024 (hi segments)
    gemm_bt8<1><<<dim3(D / 128, NKV / 128), 512, 0, stream>>>(
        x2cat, Wvct, Vt, NKV, D, D, 3 * D, 3 * D, 1.0f);

    // 5) scores: S = (T @ x2^T)/32 = (Q K^T)/32, K=3072, spread-staging 256^2
    gemm256_bt_f32<<<dim3(NKV / 256, NQ / 256), 512, 0, stream>>>(
        Tcat, x2cat, S, NQ, NKV, 3 * D, 3 * D, 3 * D, 1.0f / 32.0f);

    // 6) softmax rows in place: f32 scores -> normalized f16 P (stride 8192 f16)
    softmax_inplace<<<NQ, 256, 0, stream>>>(S, NKV);

    // 7) out = P @ V  (A = P f16, lda=8192; B^T = Vt[D][NKV], ldb=4096)
    gemm_bt8<3><<<dim3(D / 128, NQ / 128), 512, 0, stream>>>(
        (const _Float16*)S, Vt, out, NQ, D, NKV, 2 * NKV, NKV, 1.0f);
}